// Round 3
// baseline (14458.766 us; speedup 1.0000x reference)
//
#include <hip/hip_runtime.h>
#include <math.h>

namespace {
constexpr int CC = 3, OO = 6, VV = 4096;
constexpr int W0 = 64, W1 = 32, W2 = 16, WL = 16;
constexpr int L0 = W0 * W0 * OO * CC;    // 73728
constexpr int L1 = W1 * W1 * OO * CC;    // 18432
constexpr int L2 = W2 * W2 * OO * CC;    // 4608
constexpr int LLOW = WL * WL * CC;       // 768
constexpr int LT = L0 + L1 + L2 + LLOW;  // 97536
constexpr int NTOK = 2 * LT;             // 195072
constexpr int BS = 256;
constexpr int NBLK = NTOK / BS;          // 762
static_assert(NTOK % BS == 0, "grid must tile exactly");

// ws layout (bytes): [0, 65536): cbf float4[VV]; [65536, 65600): statsf[16];
// [65600, ...): part double[NBLK*4]
}  // namespace

// fp32 amp element, bit-exact: sqrt(re*re + im*im), each op rounded
__device__ __forceinline__ float amp_hi(const float* __restrict__ src, int e) {
  float re = src[2 * e], im = src[2 * e + 1];
  return __fsqrt_rn(__fadd_rn(__fmul_rn(re, re), __fmul_rn(im, im)));
}
__device__ __forceinline__ float amp_lo(const float* __restrict__ src, int e) {
  return fabsf(src[e]);
}

// One block per (level, b) group. XLA:CPU hypothesis: strict SEQUENTIAL
// left-fold fp32 reduction (acc = rn(acc + x[i]), i ascending), two-pass
// variance, div by (N-1), sqrt, +1e-8 — all fp32.
__global__ void stats_seq_kernel(const float* __restrict__ yh0,
                                 const float* __restrict__ yh1,
                                 const float* __restrict__ yh2,
                                 const float* __restrict__ yl,
                                 float* __restrict__ statsf) {
  if (threadIdx.x != 0) return;
  int grp = blockIdx.x, level = grp >> 1, b = grp & 1;
  const float* src;
  int N;
  bool cplx = (level < 3);
  if (level == 0)      { src = yh0 + (size_t)b * L0 * 2; N = L0; }
  else if (level == 1) { src = yh1 + (size_t)b * L1 * 2; N = L1; }
  else if (level == 2) { src = yh2 + (size_t)b * L2 * 2; N = L2; }
  else                 { src = yl + (size_t)b * LLOW;    N = LLOW; }

  // pass 1: mean (sequential fold, init 0: rn(0 + a0) = a0)
  float s = cplx ? amp_hi(src, 0) : amp_lo(src, 0);
  for (int i = 1; i < N; ++i) {
    float a = cplx ? amp_hi(src, i) : amp_lo(src, i);
    s = __fadd_rn(s, a);
  }
  float mean = __fdiv_rn(s, (float)N);

  // pass 2: sum of (amp - mean)^2, sequential fold
  float a0 = cplx ? amp_hi(src, 0) : amp_lo(src, 0);
  float d0 = __fsub_rn(a0, mean);
  float ss = __fmul_rn(d0, d0);
  for (int i = 1; i < N; ++i) {
    float a = cplx ? amp_hi(src, i) : amp_lo(src, i);
    float d = __fsub_rn(a, mean);
    ss = __fadd_rn(ss, __fmul_rn(d, d));
  }
  float var = __fdiv_rn(ss, (float)(N - 1));  // ddof=1
  statsf[grp] = mean;
  statsf[8 + grp] = __fadd_rn(__fsqrt_rn(var), 1e-8f);  // std + EPS
}

__global__ void cb_kernel(const float* __restrict__ emb, float4* __restrict__ cbf) {
  int v = blockIdx.x * BS + threadIdx.x;
  if (v < VV) {
    float e0 = emb[3 * v], e1 = emb[3 * v + 1], e2 = emb[3 * v + 2];
    float es = __fadd_rn(__fadd_rn(__fmul_rn(e0, e0), __fmul_rn(e1, e1)),
                         __fmul_rn(e2, e2));
    cbf[v] = make_float4(e0, e1, e2, es);
  }
}

__global__ void vq_kernel(const float* __restrict__ yh0, const float* __restrict__ yh1,
                          const float* __restrict__ yh2, const float* __restrict__ yl,
                          const float* __restrict__ emb, const float* __restrict__ scl,
                          const float4* __restrict__ cbf, const float* __restrict__ statsf,
                          float* __restrict__ out_quant, float* __restrict__ out_idx,
                          double* __restrict__ part) {
  int g = blockIdx.x * BS + threadIdx.x;
  int b = g / LT;
  int t = g - b * LT;
  int level;
  float f0, f1, f2;
  if (t < L0 + L1 + L2) {
    const float* src;
    int Wd, r;
    if (t < L0)           { level = 0; r = t;            Wd = W0; src = yh0; }
    else if (t < L0 + L1) { level = 1; r = t - L0;       Wd = W1; src = yh1; }
    else                  { level = 2; r = t - L0 - L1;  Wd = W2; src = yh2; }
    int c = r % CC;
    int r2 = r / CC;
    int o = r2 % OO;
    int r3 = r2 / OO;
    int x = r3 % Wd;
    int y = r3 / Wd;
    size_t base = ((((size_t)b * CC + c) * OO + o) * Wd + y) * Wd + x;
    float re = src[2 * base], im = src[2 * base + 1];
    float amp = __fsqrt_rn(__fadd_rn(__fmul_rn(re, re), __fmul_rn(im, im)));
    float mean = statsf[2 * level + b];
    float sdep = statsf[8 + 2 * level + b];
    f0 = __fmul_rn(__fdiv_rn(__fsub_rn(amp, mean), sdep), scl[level]);
    float den = __fadd_rn(amp, 1e-8f);
    f1 = __fdiv_rn(re, den);
    f2 = __fdiv_rn(im, den);
  } else {
    level = 3;
    int r = t - (L0 + L1 + L2);
    int c = r % CC;
    int xy = r / CC;
    int x = xy % WL;
    int y = xy / WL;
    size_t base = (((size_t)b * CC + c) * WL + y) * WL + x;
    float v = yl[base];
    float amp = fabsf(v);
    f0 = __fmul_rn(__fdiv_rn(__fsub_rn(amp, statsf[6 + b]), statsf[14 + b]), scl[3]);
    f1 = __fdiv_rn(v, __fadd_rn(amp, 1e-8f));
    f2 = 0.0f;
  }

  // dist_v = (fsum - 2*(f.e_v)) + esum_v, fp32, fma ascending-k chain
  float fsum = __fadd_rn(__fadd_rn(__fmul_rn(f0, f0), __fmul_rn(f1, f1)),
                         __fmul_rn(f2, f2));
  float best = INFINITY;
  int bi = 0;
#pragma unroll 4
  for (int v = 0; v < VV; ++v) {
    float4 e = cbf[v];
    float fe = fmaf(f2, e.z, fmaf(f1, e.y, __fmul_rn(f0, e.x)));
    float dist = __fadd_rn(__fsub_rn(fsum, __fadd_rn(fe, fe)), e.w);
    if (dist < best) { best = dist; bi = v; }  // strict <, first index wins
  }

  float q0 = emb[3 * bi], q1 = emb[3 * bi + 1], q2 = emb[3 * bi + 2];
  float d0 = __fsub_rn(q0, f0), d1 = __fsub_rn(q1, f1), d2 = __fsub_rn(q2, f2);
  // straight-through values: feats + (quant - feats), fp32 op order
  out_quant[3 * g + 0] = __fadd_rn(f0, d0);
  out_quant[3 * g + 1] = __fadd_rn(f1, d1);
  out_quant[3 * g + 2] = __fadd_rn(f2, d2);
  out_idx[g] = (float)bi;

  double sse = (double)d0 * d0 + (double)d1 * d1 + (double)d2 * d2;
  __shared__ double sh[BS];
  for (int l = 0; l < 4; ++l) {
    sh[threadIdx.x] = (level == l) ? sse : 0.0;
    __syncthreads();
    for (int off = BS / 2; off > 0; off >>= 1) {
      if ((int)threadIdx.x < off) sh[threadIdx.x] += sh[threadIdx.x + off];
      __syncthreads();
    }
    if (threadIdx.x == 0) part[4 * blockIdx.x + l] = sh[0];
    __syncthreads();
  }
}

__global__ void finalize_kernel(const double* __restrict__ part, float* __restrict__ out_loss) {
  double s[4] = {0.0, 0.0, 0.0, 0.0};
  for (int i = threadIdx.x; i < NBLK; i += BS)
    for (int l = 0; l < 4; ++l) s[l] += part[4 * i + l];
  __shared__ double sh[BS];
  __shared__ double tot;
  if (threadIdx.x == 0) tot = 0.0;
  const double cnt[4] = {2.0 * L0 * 3, 2.0 * L1 * 3, 2.0 * L2 * 3, 2.0 * LLOW * 3};
  for (int l = 0; l < 4; ++l) {
    sh[threadIdx.x] = s[l];
    __syncthreads();
    for (int off = BS / 2; off > 0; off >>= 1) {
      if ((int)threadIdx.x < off) sh[threadIdx.x] += sh[threadIdx.x + off];
      __syncthreads();
    }
    if (threadIdx.x == 0) tot += 1.25 * sh[0] / cnt[l];
    __syncthreads();
  }
  if (threadIdx.x == 0) out_loss[0] = (float)tot;
}

extern "C" void kernel_launch(void* const* d_in, const int* in_sizes, int n_in,
                              void* d_out, int out_size, void* d_ws, size_t ws_size,
                              hipStream_t stream) {
  const float* yh0 = (const float*)d_in[0];
  const float* yh1 = (const float*)d_in[1];
  const float* yh2 = (const float*)d_in[2];
  const float* yl = (const float*)d_in[3];
  const float* emb = (const float*)d_in[4];
  const float* scl = (const float*)d_in[5];

  float* out = (float*)d_out;
  float* out_quant = out;            // NTOK*3
  float* out_idx = out + 3 * NTOK;   // NTOK
  float* out_loss = out + 4 * NTOK;  // 1

  float4* cbf = (float4*)d_ws;                    // 65536 B
  float* statsf = (float*)((char*)d_ws + 65536);  // 64 B
  double* part = (double*)((char*)d_ws + 65600);  // NBLK*4*8 B

  hipLaunchKernelGGL(stats_seq_kernel, dim3(8), dim3(64), 0, stream, yh0, yh1, yh2, yl, statsf);
  hipLaunchKernelGGL(cb_kernel, dim3(VV / BS), dim3(BS), 0, stream, emb, cbf);
  hipLaunchKernelGGL(vq_kernel, dim3(NBLK), dim3(BS), 0, stream,
                     yh0, yh1, yh2, yl, emb, scl, cbf, statsf, out_quant, out_idx, part);
  hipLaunchKernelGGL(finalize_kernel, dim3(1), dim3(BS), 0, stream, part, out_loss);
}

// Round 6
// 935.665 us; speedup vs baseline: 15.4529x; 15.4529x over previous
//
#include <hip/hip_runtime.h>
#include <math.h>

namespace {
constexpr int CC = 3, OO = 6, VV = 4096;
constexpr int W0 = 64, W1 = 32, W2 = 16, WL = 16;
constexpr int L0 = W0 * W0 * OO * CC;    // 73728
constexpr int L1 = W1 * W1 * OO * CC;    // 18432
constexpr int L2 = W2 * W2 * OO * CC;    // 4608
constexpr int LLOW = WL * WL * CC;       // 768
constexpr int LT = L0 + L1 + L2 + LLOW;  // 97536
constexpr int NTOK = 2 * LT;             // 195072
constexpr int BS = 256;
constexpr int NBLK = NTOK / BS;          // 762
constexpr int CH = 8192;                 // stats chunk (floats)
static_assert(NTOK % BS == 0, "grid must tile exactly");
}  // namespace

// One block per (level, b) group. Semantics = round-3's PASSING codegen:
// amp = sqrt(fma(re, re, rn(im*im)))   [compiler-contracted in round 3]
// pass1: s = rn(s + amp_i), sequential ascending
// pass2: ss = fma(d_i, d_i, ss), d_i = rn(amp_i - mean), sequential ascending
// contract(off) + explicit fmaf pin exactly this. Structure: 256 threads
// stage amp / d into LDS chunks; thread 0 runs the dependent fold chain.
__global__ __launch_bounds__(256) void stats_kernel(const float* __restrict__ yh0,
                                                    const float* __restrict__ yh1,
                                                    const float* __restrict__ yh2,
                                                    const float* __restrict__ yl,
                                                    float* __restrict__ statsf) {
#pragma clang fp contract(off)
  __shared__ alignas(16) float lds[2 * CH];
  __shared__ float sh_mean;
  int grp = blockIdx.x, level = grp >> 1, b = grp & 1;
  const float* src;
  int N;
  bool cplx = (level < 3);
  if (level == 0)      { src = yh0 + (size_t)b * L0 * 2; N = L0; }
  else if (level == 1) { src = yh1 + (size_t)b * L1 * 2; N = L1; }
  else if (level == 2) { src = yh2 + (size_t)b * L2 * 2; N = L2; }
  else                 { src = yl + (size_t)b * LLOW;    N = LLOW; }
  int tid = threadIdx.x;
  int nchunks = (N + CH - 1) / CH;

  // amp element, round-3 contracted form
  auto amp_at = [&](int e) -> float {
#pragma clang fp contract(off)
    if (cplx) {
      float re = src[2 * e], im = src[2 * e + 1];
      return __fsqrt_rn(fmaf(re, re, __fmul_rn(im, im)));
    }
    return fabsf(src[e]);
  };

  // pass==0: stage amp; pass==1: stage d = amp - mean (UNSQUARED; the square
  // lives inside the fold's fma, as in round 3's contracted accumulate)
  auto stage = [&](int c, int pass, float mean) {
#pragma clang fp contract(off)
    int off = c * CH;
    int cnt = min(CH, N - off);
    float* dst = &lds[(c & 1) * CH];
    for (int j = tid; j < cnt; j += BS) {
      float a = amp_at(off + j);
      if (pass) a = __fsub_rn(a, mean);
      dst[j] = a;
    }
  };

  // thread-0 sequential fold of chunk c from LDS (8-deep float4 ring,
  // static indices, strictly ascending element order).
  // sq==0: s += v ; sq==1: s = fma(v, v, s)
  auto fold = [&](int c, int sq, float& s) {
#pragma clang fp contract(off)
    const float4* lb = (const float4*)&lds[(c & 1) * CH];
    int nv = min(CH, N - c * CH) >> 2;  // all chunk sizes divisible by 4
    float4 r[8];
#pragma unroll
    for (int p = 0; p < 8; ++p) r[p] = lb[p];
    int i = 0;
    for (; i + 8 < nv; i += 8) {
#pragma unroll
      for (int p = 0; p < 8; ++p) {
        float4 cur = r[p];
        r[p] = lb[i + 8 + p];
        if (sq) {
          s = fmaf(cur.x, cur.x, s);
          s = fmaf(cur.y, cur.y, s);
          s = fmaf(cur.z, cur.z, s);
          s = fmaf(cur.w, cur.w, s);
        } else {
          s = __fadd_rn(s, cur.x);
          s = __fadd_rn(s, cur.y);
          s = __fadd_rn(s, cur.z);
          s = __fadd_rn(s, cur.w);
        }
      }
    }
#pragma unroll
    for (int p = 0; p < 8; ++p) {
      float4 cur = r[p];
      if (sq) {
        s = fmaf(cur.x, cur.x, s);
        s = fmaf(cur.y, cur.y, s);
        s = fmaf(cur.z, cur.z, s);
        s = fmaf(cur.w, cur.w, s);
      } else {
        s = __fadd_rn(s, cur.x);
        s = __fadd_rn(s, cur.y);
        s = __fadd_rn(s, cur.z);
        s = __fadd_rn(s, cur.w);
      }
    }
  };

  // ---- pass 1: sum of amp ----
  float s = 0.0f;
  stage(0, 0, 0.0f);
  __syncthreads();
  for (int c = 0; c < nchunks; ++c) {
    if (c + 1 < nchunks) stage(c + 1, 0, 0.0f);  // overlaps thread-0 fold
    if (tid == 0) fold(c, 0, s);
    __syncthreads();
  }
  if (tid == 0) sh_mean = __fdiv_rn(s, (float)N);
  __syncthreads();
  float mean = sh_mean;

  // ---- pass 2: sum via fma(d, d, acc) ----
  float ss = 0.0f;
  stage(0, 1, mean);
  __syncthreads();
  for (int c = 0; c < nchunks; ++c) {
    if (c + 1 < nchunks) stage(c + 1, 1, mean);
    if (tid == 0) fold(c, 1, ss);
    __syncthreads();
  }
  if (tid == 0) {
    float var = __fdiv_rn(ss, (float)(N - 1));  // ddof=1
    statsf[grp] = mean;
    statsf[8 + grp] = __fadd_rn(__fsqrt_rn(var), 1e-8f);  // std + EPS
  }
}

// ---- below here: VERBATIM round-4 text (round-3-proven semantics), no pragmas ----

__global__ void cb_kernel(const float* __restrict__ emb, float4* __restrict__ cbf) {
  int v = blockIdx.x * BS + threadIdx.x;
  if (v < VV) {
    float e0 = emb[3 * v], e1 = emb[3 * v + 1], e2 = emb[3 * v + 2];
    float es = __fadd_rn(__fadd_rn(__fmul_rn(e0, e0), __fmul_rn(e1, e1)),
                         __fmul_rn(e2, e2));
    cbf[v] = make_float4(e0, e1, e2, es);
  }
}

__global__ __launch_bounds__(256) void vq_kernel(
    const float* __restrict__ yh0, const float* __restrict__ yh1,
    const float* __restrict__ yh2, const float* __restrict__ yl,
    const float* __restrict__ emb, const float* __restrict__ scl,
    const float4* __restrict__ cbf, const float* __restrict__ statsf,
    float* __restrict__ out_quant, float* __restrict__ out_idx,
    double* __restrict__ part) {
  __shared__ float4 cb[VV];  // 64 KB
  for (int v = threadIdx.x; v < VV; v += BS) cb[v] = cbf[v];

  int g = blockIdx.x * BS + threadIdx.x;
  int b = g / LT;
  int t = g - b * LT;
  int level;
  float f0, f1, f2;
  if (t < L0 + L1 + L2) {
    const float* src;
    int Wd, r;
    if (t < L0)           { level = 0; r = t;           Wd = W0; src = yh0; }
    else if (t < L0 + L1) { level = 1; r = t - L0;      Wd = W1; src = yh1; }
    else                  { level = 2; r = t - L0 - L1; Wd = W2; src = yh2; }
    int c = r % CC;
    int r2 = r / CC;
    int o = r2 % OO;
    int r3 = r2 / OO;
    int x = r3 % Wd;
    int y = r3 / Wd;
    size_t base = ((((size_t)b * CC + c) * OO + o) * Wd + y) * Wd + x;
    float re = src[2 * base], im = src[2 * base + 1];
    float amp = __fsqrt_rn(__fadd_rn(__fmul_rn(re, re), __fmul_rn(im, im)));
    float mean = statsf[2 * level + b];
    float sdep = statsf[8 + 2 * level + b];
    f0 = __fmul_rn(__fdiv_rn(__fsub_rn(amp, mean), sdep), scl[level]);
    float den = __fadd_rn(amp, 1e-8f);
    f1 = __fdiv_rn(re, den);
    f2 = __fdiv_rn(im, den);
  } else {
    level = 3;
    int r = t - (L0 + L1 + L2);
    int c = r % CC;
    int xy = r / CC;
    int x = xy % WL;
    int y = xy / WL;
    size_t base = (((size_t)b * CC + c) * WL + y) * WL + x;
    float v = yl[base];
    float amp = fabsf(v);
    f0 = __fmul_rn(__fdiv_rn(__fsub_rn(amp, statsf[6 + b]), statsf[14 + b]), scl[3]);
    f1 = __fdiv_rn(v, __fadd_rn(amp, 1e-8f));
    f2 = 0.0f;
  }

  float fsum = __fadd_rn(__fadd_rn(__fmul_rn(f0, f0), __fmul_rn(f1, f1)),
                         __fmul_rn(f2, f2));
  __syncthreads();  // codebook staged
  float best = INFINITY;
  int bi = 0;
#pragma unroll 4
  for (int v = 0; v < VV; ++v) {
    float4 e = cb[v];  // uniform address -> LDS broadcast
    float fe = fmaf(f2, e.z, fmaf(f1, e.y, __fmul_rn(f0, e.x)));
    float dist = __fadd_rn(__fsub_rn(fsum, __fadd_rn(fe, fe)), e.w);
    if (dist < best) { best = dist; bi = v; }  // strict <, first index wins
  }

  float q0 = emb[3 * bi], q1 = emb[3 * bi + 1], q2 = emb[3 * bi + 2];
  float d0 = __fsub_rn(q0, f0), d1 = __fsub_rn(q1, f1), d2 = __fsub_rn(q2, f2);
  out_quant[3 * g + 0] = __fadd_rn(f0, d0);
  out_quant[3 * g + 1] = __fadd_rn(f1, d1);
  out_quant[3 * g + 2] = __fadd_rn(f2, d2);
  out_idx[g] = (float)bi;

  double sse = (double)d0 * d0 + (double)d1 * d1 + (double)d2 * d2;
  __shared__ double sh[BS];
  for (int l = 0; l < 4; ++l) {
    sh[threadIdx.x] = (level == l) ? sse : 0.0;
    __syncthreads();
    for (int off = BS / 2; off > 0; off >>= 1) {
      if ((int)threadIdx.x < off) sh[threadIdx.x] += sh[threadIdx.x + off];
      __syncthreads();
    }
    if (threadIdx.x == 0) part[4 * blockIdx.x + l] = sh[0];
    __syncthreads();
  }
}

__global__ void finalize_kernel(const double* __restrict__ part, float* __restrict__ out_loss) {
  double s[4] = {0.0, 0.0, 0.0, 0.0};
  for (int i = threadIdx.x; i < NBLK; i += BS)
    for (int l = 0; l < 4; ++l) s[l] += part[4 * i + l];
  __shared__ double sh[BS];
  __shared__ double tot;
  if (threadIdx.x == 0) tot = 0.0;
  const double cnt[4] = {2.0 * L0 * 3, 2.0 * L1 * 3, 2.0 * L2 * 3, 2.0 * LLOW * 3};
  for (int l = 0; l < 4; ++l) {
    sh[threadIdx.x] = s[l];
    __syncthreads();
    for (int off = BS / 2; off > 0; off >>= 1) {
      if ((int)threadIdx.x < off) sh[threadIdx.x] += sh[threadIdx.x + off];
      __syncthreads();
    }
    if (threadIdx.x == 0) tot += 1.25 * sh[0] / cnt[l];
    __syncthreads();
  }
  if (threadIdx.x == 0) out_loss[0] = (float)tot;
}

extern "C" void kernel_launch(void* const* d_in, const int* in_sizes, int n_in,
                              void* d_out, int out_size, void* d_ws, size_t ws_size,
                              hipStream_t stream) {
  const float* yh0 = (const float*)d_in[0];
  const float* yh1 = (const float*)d_in[1];
  const float* yh2 = (const float*)d_in[2];
  const float* yl = (const float*)d_in[3];
  const float* emb = (const float*)d_in[4];
  const float* scl = (const float*)d_in[5];

  float* out = (float*)d_out;
  float* out_quant = out;            // NTOK*3
  float* out_idx = out + 3 * NTOK;   // NTOK
  float* out_loss = out + 4 * NTOK;  // 1

  float4* cbf = (float4*)d_ws;                    // 65536 B
  float* statsf = (float*)((char*)d_ws + 65536);  // 64 B
  double* part = (double*)((char*)d_ws + 65600);  // NBLK*4*8 B

  hipLaunchKernelGGL(cb_kernel, dim3(VV / BS), dim3(BS), 0, stream, emb, cbf);
  hipLaunchKernelGGL(stats_kernel, dim3(8), dim3(BS), 0, stream, yh0, yh1, yh2, yl, statsf);
  hipLaunchKernelGGL(vq_kernel, dim3(NBLK), dim3(BS), 0, stream,
                     yh0, yh1, yh2, yl, emb, scl, cbf, statsf, out_quant, out_idx, part);
  hipLaunchKernelGGL(finalize_kernel, dim3(1), dim3(BS), 0, stream, part, out_loss);
}

// Round 7
// 833.730 us; speedup vs baseline: 17.3423x; 1.1223x over previous
//
#include <hip/hip_runtime.h>
#include <math.h>

namespace {
constexpr int CC = 3, OO = 6, VV = 4096;
constexpr int W0 = 64, W1 = 32, W2 = 16, WL = 16;
constexpr int L0 = W0 * W0 * OO * CC;    // 73728
constexpr int L1 = W1 * W1 * OO * CC;    // 18432
constexpr int L2 = W2 * W2 * OO * CC;    // 4608
constexpr int LLOW = WL * WL * CC;       // 768
constexpr int LT = L0 + L1 + L2 + LLOW;  // 97536
constexpr int NTOK = 2 * LT;             // 195072
constexpr int BS = 256;
constexpr int NBLK = NTOK / BS;          // 762
constexpr int CH = 8192;                 // stats chunk (floats)
static_assert(NTOK % BS == 0, "grid must tile exactly");
}  // namespace

// One block per (level, b) group. Semantics = round-6 PASSING kernel (pinned):
// amp = sqrt(fma(re, re, rn(im*im)))
// pass1: s = rn(s + amp_i), sequential ascending
// pass2: ss = fma(d_i, d_i, ss), d_i = rn(amp_i - mean), sequential ascending
// Structure: waves 1-3 stage amp/d into LDS chunks; wave 0 lane 0 runs the
// dependent fold chain with a 2-bank software pipeline (no register ring).
__global__ __launch_bounds__(256) void stats_kernel(const float* __restrict__ yh0,
                                                    const float* __restrict__ yh1,
                                                    const float* __restrict__ yh2,
                                                    const float* __restrict__ yl,
                                                    float* __restrict__ statsf) {
#pragma clang fp contract(off)
  __shared__ alignas(16) float lds[2 * CH];
  __shared__ float sh_mean;
  int grp = blockIdx.x, level = grp >> 1, b = grp & 1;
  const float* src;
  int N;
  bool cplx = (level < 3);
  if (level == 0)      { src = yh0 + (size_t)b * L0 * 2; N = L0; }
  else if (level == 1) { src = yh1 + (size_t)b * L1 * 2; N = L1; }
  else if (level == 2) { src = yh2 + (size_t)b * L2 * 2; N = L2; }
  else                 { src = yl + (size_t)b * LLOW;    N = LLOW; }
  int tid = threadIdx.x;
  int nchunks = (N + CH - 1) / CH;

  // amp element (pinned round-6 form)
  auto amp_at = [&](int e) -> float {
#pragma clang fp contract(off)
    if (cplx) {
      float re = src[2 * e], im = src[2 * e + 1];
      return __fsqrt_rn(fmaf(re, re, __fmul_rn(im, im)));
    }
    return fabsf(src[e]);
  };

  // pass==0: stage amp; pass==1: stage d = amp - mean (square lives in fold's fma)
  // threads with tid >= first participate, index j = tid-first, step `step`
  auto stage = [&](int c, int pass, float mean, int first, int step) {
#pragma clang fp contract(off)
    if (tid < first) return;
    int off = c * CH;
    int cnt = min(CH, N - off);
    float* dst = &lds[(c & 1) * CH];
    for (int j = tid - first; j < cnt; j += step) {
      float a = amp_at(off + j);
      if (pass) a = __fsub_rn(a, mean);
      dst[j] = a;
    }
  };

  // lane-0 sequential fold, 2-bank pipeline, strictly ascending element order.
  // All chunk sizes are multiples of 64 floats (16 float4), nv >= 32.
  auto fold_sum = [&](int c, float& s) {
#pragma clang fp contract(off)
    const float4* lb = (const float4*)&lds[(c & 1) * CH];
    int nv = min(CH, N - c * CH) >> 2;
    float4 A[8], B[8];
#pragma unroll
    for (int p = 0; p < 8; ++p) A[p] = lb[p];
    int iters = nv >> 4;
    for (int it = 0; it < iters; ++it) {
      const int i = it << 4;
#pragma unroll
      for (int p = 0; p < 8; ++p) B[p] = lb[i + 8 + p];
#pragma unroll
      for (int p = 0; p < 8; ++p) {
        s = __fadd_rn(s, A[p].x);
        s = __fadd_rn(s, A[p].y);
        s = __fadd_rn(s, A[p].z);
        s = __fadd_rn(s, A[p].w);
      }
      if (it + 1 < iters) {
#pragma unroll
        for (int p = 0; p < 8; ++p) A[p] = lb[i + 16 + p];
      }
#pragma unroll
      for (int p = 0; p < 8; ++p) {
        s = __fadd_rn(s, B[p].x);
        s = __fadd_rn(s, B[p].y);
        s = __fadd_rn(s, B[p].z);
        s = __fadd_rn(s, B[p].w);
      }
    }
  };

  auto fold_sq = [&](int c, float& s) {
#pragma clang fp contract(off)
    const float4* lb = (const float4*)&lds[(c & 1) * CH];
    int nv = min(CH, N - c * CH) >> 2;
    float4 A[8], B[8];
#pragma unroll
    for (int p = 0; p < 8; ++p) A[p] = lb[p];
    int iters = nv >> 4;
    for (int it = 0; it < iters; ++it) {
      const int i = it << 4;
#pragma unroll
      for (int p = 0; p < 8; ++p) B[p] = lb[i + 8 + p];
#pragma unroll
      for (int p = 0; p < 8; ++p) {
        s = fmaf(A[p].x, A[p].x, s);
        s = fmaf(A[p].y, A[p].y, s);
        s = fmaf(A[p].z, A[p].z, s);
        s = fmaf(A[p].w, A[p].w, s);
      }
      if (it + 1 < iters) {
#pragma unroll
        for (int p = 0; p < 8; ++p) A[p] = lb[i + 16 + p];
      }
#pragma unroll
      for (int p = 0; p < 8; ++p) {
        s = fmaf(B[p].x, B[p].x, s);
        s = fmaf(B[p].y, B[p].y, s);
        s = fmaf(B[p].z, B[p].z, s);
        s = fmaf(B[p].w, B[p].w, s);
      }
    }
  };

  // ---- pass 1: sum of amp ----
  float s = 0.0f;
  stage(0, 0, 0.0f, 0, BS);  // prologue: all threads
  __syncthreads();
  for (int c = 0; c < nchunks; ++c) {
    if (c + 1 < nchunks) stage(c + 1, 0, 0.0f, 64, BS - 64);  // waves 1-3 only
    if (tid == 0) fold_sum(c, s);
    __syncthreads();
  }
  if (tid == 0) sh_mean = __fdiv_rn(s, (float)N);
  __syncthreads();
  float mean = sh_mean;

  // ---- pass 2: sum via fma(d, d, acc) ----
  float ss = 0.0f;
  stage(0, 1, mean, 0, BS);
  __syncthreads();
  for (int c = 0; c < nchunks; ++c) {
    if (c + 1 < nchunks) stage(c + 1, 1, mean, 64, BS - 64);
    if (tid == 0) fold_sq(c, ss);
    __syncthreads();
  }
  if (tid == 0) {
    float var = __fdiv_rn(ss, (float)(N - 1));  // ddof=1
    statsf[grp] = mean;
    statsf[8 + grp] = __fadd_rn(__fsqrt_rn(var), 1e-8f);  // std + EPS
  }
}

// ---- below here: VERBATIM round-6 text (proven semantics), no changes ----

__global__ void cb_kernel(const float* __restrict__ emb, float4* __restrict__ cbf) {
  int v = blockIdx.x * BS + threadIdx.x;
  if (v < VV) {
    float e0 = emb[3 * v], e1 = emb[3 * v + 1], e2 = emb[3 * v + 2];
    float es = __fadd_rn(__fadd_rn(__fmul_rn(e0, e0), __fmul_rn(e1, e1)),
                         __fmul_rn(e2, e2));
    cbf[v] = make_float4(e0, e1, e2, es);
  }
}

__global__ __launch_bounds__(256) void vq_kernel(
    const float* __restrict__ yh0, const float* __restrict__ yh1,
    const float* __restrict__ yh2, const float* __restrict__ yl,
    const float* __restrict__ emb, const float* __restrict__ scl,
    const float4* __restrict__ cbf, const float* __restrict__ statsf,
    float* __restrict__ out_quant, float* __restrict__ out_idx,
    double* __restrict__ part) {
  __shared__ float4 cb[VV];  // 64 KB
  for (int v = threadIdx.x; v < VV; v += BS) cb[v] = cbf[v];

  int g = blockIdx.x * BS + threadIdx.x;
  int b = g / LT;
  int t = g - b * LT;
  int level;
  float f0, f1, f2;
  if (t < L0 + L1 + L2) {
    const float* src;
    int Wd, r;
    if (t < L0)           { level = 0; r = t;           Wd = W0; src = yh0; }
    else if (t < L0 + L1) { level = 1; r = t - L0;      Wd = W1; src = yh1; }
    else                  { level = 2; r = t - L0 - L1; Wd = W2; src = yh2; }
    int c = r % CC;
    int r2 = r / CC;
    int o = r2 % OO;
    int r3 = r2 / OO;
    int x = r3 % Wd;
    int y = r3 / Wd;
    size_t base = ((((size_t)b * CC + c) * OO + o) * Wd + y) * Wd + x;
    float re = src[2 * base], im = src[2 * base + 1];
    float amp = __fsqrt_rn(__fadd_rn(__fmul_rn(re, re), __fmul_rn(im, im)));
    float mean = statsf[2 * level + b];
    float sdep = statsf[8 + 2 * level + b];
    f0 = __fmul_rn(__fdiv_rn(__fsub_rn(amp, mean), sdep), scl[level]);
    float den = __fadd_rn(amp, 1e-8f);
    f1 = __fdiv_rn(re, den);
    f2 = __fdiv_rn(im, den);
  } else {
    level = 3;
    int r = t - (L0 + L1 + L2);
    int c = r % CC;
    int xy = r / CC;
    int x = xy % WL;
    int y = xy / WL;
    size_t base = (((size_t)b * CC + c) * WL + y) * WL + x;
    float v = yl[base];
    float amp = fabsf(v);
    f0 = __fmul_rn(__fdiv_rn(__fsub_rn(amp, statsf[6 + b]), statsf[14 + b]), scl[3]);
    f1 = __fdiv_rn(v, __fadd_rn(amp, 1e-8f));
    f2 = 0.0f;
  }

  float fsum = __fadd_rn(__fadd_rn(__fmul_rn(f0, f0), __fmul_rn(f1, f1)),
                         __fmul_rn(f2, f2));
  __syncthreads();  // codebook staged
  float best = INFINITY;
  int bi = 0;
#pragma unroll 4
  for (int v = 0; v < VV; ++v) {
    float4 e = cb[v];  // uniform address -> LDS broadcast
    float fe = fmaf(f2, e.z, fmaf(f1, e.y, __fmul_rn(f0, e.x)));
    float dist = __fadd_rn(__fsub_rn(fsum, __fadd_rn(fe, fe)), e.w);
    if (dist < best) { best = dist; bi = v; }  // strict <, first index wins
  }

  float q0 = emb[3 * bi], q1 = emb[3 * bi + 1], q2 = emb[3 * bi + 2];
  float d0 = __fsub_rn(q0, f0), d1 = __fsub_rn(q1, f1), d2 = __fsub_rn(q2, f2);
  out_quant[3 * g + 0] = __fadd_rn(f0, d0);
  out_quant[3 * g + 1] = __fadd_rn(f1, d1);
  out_quant[3 * g + 2] = __fadd_rn(f2, d2);
  out_idx[g] = (float)bi;

  double sse = (double)d0 * d0 + (double)d1 * d1 + (double)d2 * d2;
  __shared__ double sh[BS];
  for (int l = 0; l < 4; ++l) {
    sh[threadIdx.x] = (level == l) ? sse : 0.0;
    __syncthreads();
    for (int off = BS / 2; off > 0; off >>= 1) {
      if ((int)threadIdx.x < off) sh[threadIdx.x] += sh[threadIdx.x + off];
      __syncthreads();
    }
    if (threadIdx.x == 0) part[4 * blockIdx.x + l] = sh[0];
    __syncthreads();
  }
}

__global__ void finalize_kernel(const double* __restrict__ part, float* __restrict__ out_loss) {
  double s[4] = {0.0, 0.0, 0.0, 0.0};
  for (int i = threadIdx.x; i < NBLK; i += BS)
    for (int l = 0; l < 4; ++l) s[l] += part[4 * i + l];
  __shared__ double sh[BS];
  __shared__ double tot;
  if (threadIdx.x == 0) tot = 0.0;
  const double cnt[4] = {2.0 * L0 * 3, 2.0 * L1 * 3, 2.0 * L2 * 3, 2.0 * LLOW * 3};
  for (int l = 0; l < 4; ++l) {
    sh[threadIdx.x] = s[l];
    __syncthreads();
    for (int off = BS / 2; off > 0; off >>= 1) {
      if ((int)threadIdx.x < off) sh[threadIdx.x] += sh[threadIdx.x + off];
      __syncthreads();
    }
    if (threadIdx.x == 0) tot += 1.25 * sh[0] / cnt[l];
    __syncthreads();
  }
  if (threadIdx.x == 0) out_loss[0] = (float)tot;
}

extern "C" void kernel_launch(void* const* d_in, const int* in_sizes, int n_in,
                              void* d_out, int out_size, void* d_ws, size_t ws_size,
                              hipStream_t stream) {
  const float* yh0 = (const float*)d_in[0];
  const float* yh1 = (const float*)d_in[1];
  const float* yh2 = (const float*)d_in[2];
  const float* yl = (const float*)d_in[3];
  const float* emb = (const float*)d_in[4];
  const float* scl = (const float*)d_in[5];

  float* out = (float*)d_out;
  float* out_quant = out;            // NTOK*3
  float* out_idx = out + 3 * NTOK;   // NTOK
  float* out_loss = out + 4 * NTOK;  // 1

  float4* cbf = (float4*)d_ws;                    // 65536 B
  float* statsf = (float*)((char*)d_ws + 65536);  // 64 B
  double* part = (double*)((char*)d_ws + 65600);  // NBLK*4*8 B

  hipLaunchKernelGGL(cb_kernel, dim3(VV / BS), dim3(BS), 0, stream, emb, cbf);
  hipLaunchKernelGGL(stats_kernel, dim3(8), dim3(BS), 0, stream, yh0, yh1, yh2, yl, statsf);
  hipLaunchKernelGGL(vq_kernel, dim3(NBLK), dim3(BS), 0, stream,
                     yh0, yh1, yh2, yl, emb, scl, cbf, statsf, out_quant, out_idx, part);
  hipLaunchKernelGGL(finalize_kernel, dim3(1), dim3(BS), 0, stream, part, out_loss);
}

// Round 8
// 782.630 us; speedup vs baseline: 18.4746x; 1.0653x over previous
//
#include <hip/hip_runtime.h>
#include <math.h>

namespace {
constexpr int CC = 3, OO = 6, VV = 4096;
constexpr int W0 = 64, W1 = 32, W2 = 16, WL = 16;
constexpr int L0 = W0 * W0 * OO * CC;    // 73728
constexpr int L1 = W1 * W1 * OO * CC;    // 18432
constexpr int L2 = W2 * W2 * OO * CC;    // 4608
constexpr int LLOW = WL * WL * CC;       // 768
constexpr int LT = L0 + L1 + L2 + LLOW;  // 97536
constexpr int NTOK = 2 * LT;             // 195072
constexpr int BS = 256;
constexpr int NBLK = NTOK / BS;          // 762
constexpr int CH = 8192;                 // stats chunk (floats)
static_assert(NTOK % BS == 0, "grid must tile exactly");
}  // namespace

// One block per (level, b) group. Semantics = round-6/7 PASSING kernels (pinned):
// amp = sqrt(fma(re, re, rn(im*im)))
// pass1: s = rn(s + amp_i), sequential ascending
// pass2: ss = fma(d_i, d_i, ss), d_i = rn(amp_i - mean), sequential ascending
// Structure: waves 1-3 stage amp/d into LDS chunks; wave 0 lane 0 runs the
// dependent fold chain. Banks of 16 float4: 64 dependent adds (~256 cyc)
// cover each 16-ds_read batch (~120 cyc) with 2x margin.
__global__ __launch_bounds__(256) void stats_kernel(const float* __restrict__ yh0,
                                                    const float* __restrict__ yh1,
                                                    const float* __restrict__ yh2,
                                                    const float* __restrict__ yl,
                                                    float* __restrict__ statsf) {
#pragma clang fp contract(off)
  __shared__ alignas(16) float lds[2 * CH];
  __shared__ float sh_mean;
  int grp = blockIdx.x, level = grp >> 1, b = grp & 1;
  const float* src;
  int N;
  bool cplx = (level < 3);
  if (level == 0)      { src = yh0 + (size_t)b * L0 * 2; N = L0; }
  else if (level == 1) { src = yh1 + (size_t)b * L1 * 2; N = L1; }
  else if (level == 2) { src = yh2 + (size_t)b * L2 * 2; N = L2; }
  else                 { src = yl + (size_t)b * LLOW;    N = LLOW; }
  int tid = threadIdx.x;
  int nchunks = (N + CH - 1) / CH;

  // amp element (pinned form)
  auto amp_at = [&](int e) -> float {
#pragma clang fp contract(off)
    if (cplx) {
      float re = src[2 * e], im = src[2 * e + 1];
      return __fsqrt_rn(fmaf(re, re, __fmul_rn(im, im)));
    }
    return fabsf(src[e]);
  };

  // pass==0: stage amp; pass==1: stage d = amp - mean (square lives in fold's fma)
  auto stage = [&](int c, int pass, float mean, int first, int step) {
#pragma clang fp contract(off)
    if (tid < first) return;
    int off = c * CH;
    int cnt = min(CH, N - off);
    float* dst = &lds[(c & 1) * CH];
    for (int j = tid - first; j < cnt; j += step) {
      float a = amp_at(off + j);
      if (pass) a = __fsub_rn(a, mean);
      dst[j] = a;
    }
  };

  // lane-0 sequential fold, 2-bank (16 float4 each) pipeline, strictly
  // ascending element order. All chunk float4-counts divide 32.
  auto fold_sum = [&](int c, float& s) {
#pragma clang fp contract(off)
    const float4* lb = (const float4*)&lds[(c & 1) * CH];
    int nv = min(CH, N - c * CH) >> 2;
    float4 A[16], B[16];
#pragma unroll
    for (int p = 0; p < 16; ++p) A[p] = lb[p];
    int iters = nv >> 5;
    for (int it = 0; it < iters; ++it) {
      const int i = it << 5;
#pragma unroll
      for (int p = 0; p < 16; ++p) B[p] = lb[i + 16 + p];
#pragma unroll
      for (int p = 0; p < 16; ++p) {
        s = __fadd_rn(s, A[p].x);
        s = __fadd_rn(s, A[p].y);
        s = __fadd_rn(s, A[p].z);
        s = __fadd_rn(s, A[p].w);
      }
      if (it + 1 < iters) {
#pragma unroll
        for (int p = 0; p < 16; ++p) A[p] = lb[i + 32 + p];
      }
#pragma unroll
      for (int p = 0; p < 16; ++p) {
        s = __fadd_rn(s, B[p].x);
        s = __fadd_rn(s, B[p].y);
        s = __fadd_rn(s, B[p].z);
        s = __fadd_rn(s, B[p].w);
      }
    }
  };

  auto fold_sq = [&](int c, float& s) {
#pragma clang fp contract(off)
    const float4* lb = (const float4*)&lds[(c & 1) * CH];
    int nv = min(CH, N - c * CH) >> 2;
    float4 A[16], B[16];
#pragma unroll
    for (int p = 0; p < 16; ++p) A[p] = lb[p];
    int iters = nv >> 5;
    for (int it = 0; it < iters; ++it) {
      const int i = it << 5;
#pragma unroll
      for (int p = 0; p < 16; ++p) B[p] = lb[i + 16 + p];
#pragma unroll
      for (int p = 0; p < 16; ++p) {
        s = fmaf(A[p].x, A[p].x, s);
        s = fmaf(A[p].y, A[p].y, s);
        s = fmaf(A[p].z, A[p].z, s);
        s = fmaf(A[p].w, A[p].w, s);
      }
      if (it + 1 < iters) {
#pragma unroll
        for (int p = 0; p < 16; ++p) A[p] = lb[i + 32 + p];
      }
#pragma unroll
      for (int p = 0; p < 16; ++p) {
        s = fmaf(B[p].x, B[p].x, s);
        s = fmaf(B[p].y, B[p].y, s);
        s = fmaf(B[p].z, B[p].z, s);
        s = fmaf(B[p].w, B[p].w, s);
      }
    }
  };

  // ---- pass 1: sum of amp ----
  float s = 0.0f;
  stage(0, 0, 0.0f, 0, BS);  // prologue: all threads
  __syncthreads();
  for (int c = 0; c < nchunks; ++c) {
    if (c + 1 < nchunks) stage(c + 1, 0, 0.0f, 64, BS - 64);  // waves 1-3 only
    if (tid == 0) fold_sum(c, s);
    __syncthreads();
  }
  if (tid == 0) sh_mean = __fdiv_rn(s, (float)N);
  __syncthreads();
  float mean = sh_mean;

  // ---- pass 2: sum via fma(d, d, acc) ----
  float ss = 0.0f;
  stage(0, 1, mean, 0, BS);
  __syncthreads();
  for (int c = 0; c < nchunks; ++c) {
    if (c + 1 < nchunks) stage(c + 1, 1, mean, 64, BS - 64);
    if (tid == 0) fold_sq(c, ss);
    __syncthreads();
  }
  if (tid == 0) {
    float var = __fdiv_rn(ss, (float)(N - 1));  // ddof=1
    statsf[grp] = mean;
    statsf[8 + grp] = __fadd_rn(__fsqrt_rn(var), 1e-8f);  // std + EPS
  }
}

__global__ void cb_kernel(const float* __restrict__ emb, float4* __restrict__ cbf) {
  int v = blockIdx.x * BS + threadIdx.x;
  if (v < VV) {
    float e0 = emb[3 * v], e1 = emb[3 * v + 1], e2 = emb[3 * v + 2];
    float es = __fadd_rn(__fadd_rn(__fmul_rn(e0, e0), __fmul_rn(e1, e1)),
                         __fmul_rn(e2, e2));
    cbf[v] = make_float4(e0, e1, e2, es);
  }
}

__global__ __launch_bounds__(256) void vq_kernel(
    const float* __restrict__ yh0, const float* __restrict__ yh1,
    const float* __restrict__ yh2, const float* __restrict__ yl,
    const float* __restrict__ emb, const float* __restrict__ scl,
    const float4* __restrict__ cbf, const float* __restrict__ statsf,
    float* __restrict__ out_quant, float* __restrict__ out_idx,
    double* __restrict__ part) {
  __shared__ float4 cb[VV];  // 64 KB
  for (int v = threadIdx.x; v < VV; v += BS) cb[v] = cbf[v];

  int g = blockIdx.x * BS + threadIdx.x;
  int b = g / LT;
  int t = g - b * LT;
  int level;
  float f0, f1, f2;
  if (t < L0 + L1 + L2) {
    const float* src;
    int Wd, r;
    if (t < L0)           { level = 0; r = t;           Wd = W0; src = yh0; }
    else if (t < L0 + L1) { level = 1; r = t - L0;      Wd = W1; src = yh1; }
    else                  { level = 2; r = t - L0 - L1; Wd = W2; src = yh2; }
    int c = r % CC;
    int r2 = r / CC;
    int o = r2 % OO;
    int r3 = r2 / OO;
    int x = r3 % Wd;
    int y = r3 / Wd;
    size_t base = ((((size_t)b * CC + c) * OO + o) * Wd + y) * Wd + x;
    float re = src[2 * base], im = src[2 * base + 1];
    float amp = __fsqrt_rn(__fadd_rn(__fmul_rn(re, re), __fmul_rn(im, im)));
    float mean = statsf[2 * level + b];
    float sdep = statsf[8 + 2 * level + b];
    f0 = __fmul_rn(__fdiv_rn(__fsub_rn(amp, mean), sdep), scl[level]);
    float den = __fadd_rn(amp, 1e-8f);
    f1 = __fdiv_rn(re, den);
    f2 = __fdiv_rn(im, den);
  } else {
    level = 3;
    int r = t - (L0 + L1 + L2);
    int c = r % CC;
    int xy = r / CC;
    int x = xy % WL;
    int y = xy / WL;
    size_t base = (((size_t)b * CC + c) * WL + y) * WL + x;
    float v = yl[base];
    float amp = fabsf(v);
    f0 = __fmul_rn(__fdiv_rn(__fsub_rn(amp, statsf[6 + b]), statsf[14 + b]), scl[3]);
    f1 = __fdiv_rn(v, __fadd_rn(amp, 1e-8f));
    f2 = 0.0f;
  }

  float fsum = __fadd_rn(__fadd_rn(__fmul_rn(f0, f0), __fmul_rn(f1, f1)),
                         __fmul_rn(f2, f2));
  // m_i = rn(2*f_i) is EXACT, and rn(2x)=2rn(x) distributes through the fma
  // chain, so fe2 == 2*fe bit-exactly (== reference's (2f)@E^T k-chain).
  float m0 = __fmul_rn(f0, 2.0f), m1 = __fmul_rn(f1, 2.0f), m2 = __fmul_rn(f2, 2.0f);
  __syncthreads();  // codebook staged
  float best = INFINITY;
  int bi = 0;
#pragma unroll 8
  for (int v = 0; v < VV; ++v) {
    float4 e = cb[v];  // uniform address -> LDS broadcast
    float fe2 = fmaf(m2, e.z, fmaf(m1, e.y, __fmul_rn(m0, e.x)));
    float dist = __fadd_rn(__fsub_rn(fsum, fe2), e.w);
    if (dist < best) { best = dist; bi = v; }  // strict <, first index wins
  }

  float q0 = emb[3 * bi], q1 = emb[3 * bi + 1], q2 = emb[3 * bi + 2];
  float d0 = __fsub_rn(q0, f0), d1 = __fsub_rn(q1, f1), d2 = __fsub_rn(q2, f2);
  out_quant[3 * g + 0] = __fadd_rn(f0, d0);
  out_quant[3 * g + 1] = __fadd_rn(f1, d1);
  out_quant[3 * g + 2] = __fadd_rn(f2, d2);
  out_idx[g] = (float)bi;

  double sse = (double)d0 * d0 + (double)d1 * d1 + (double)d2 * d2;
  __shared__ double sh[BS];
  for (int l = 0; l < 4; ++l) {
    sh[threadIdx.x] = (level == l) ? sse : 0.0;
    __syncthreads();
    for (int off = BS / 2; off > 0; off >>= 1) {
      if ((int)threadIdx.x < off) sh[threadIdx.x] += sh[threadIdx.x + off];
      __syncthreads();
    }
    if (threadIdx.x == 0) part[4 * blockIdx.x + l] = sh[0];
    __syncthreads();
  }
}

__global__ void finalize_kernel(const double* __restrict__ part, float* __restrict__ out_loss) {
  double s[4] = {0.0, 0.0, 0.0, 0.0};
  for (int i = threadIdx.x; i < NBLK; i += BS)
    for (int l = 0; l < 4; ++l) s[l] += part[4 * i + l];
  __shared__ double sh[BS];
  __shared__ double tot;
  if (threadIdx.x == 0) tot = 0.0;
  const double cnt[4] = {2.0 * L0 * 3, 2.0 * L1 * 3, 2.0 * L2 * 3, 2.0 * LLOW * 3};
  for (int l = 0; l < 4; ++l) {
    sh[threadIdx.x] = s[l];
    __syncthreads();
    for (int off = BS / 2; off > 0; off >>= 1) {
      if ((int)threadIdx.x < off) sh[threadIdx.x] += sh[threadIdx.x + off];
      __syncthreads();
    }
    if (threadIdx.x == 0) tot += 1.25 * sh[0] / cnt[l];
    __syncthreads();
  }
  if (threadIdx.x == 0) out_loss[0] = (float)tot;
}

extern "C" void kernel_launch(void* const* d_in, const int* in_sizes, int n_in,
                              void* d_out, int out_size, void* d_ws, size_t ws_size,
                              hipStream_t stream) {
  const float* yh0 = (const float*)d_in[0];
  const float* yh1 = (const float*)d_in[1];
  const float* yh2 = (const float*)d_in[2];
  const float* yl = (const float*)d_in[3];
  const float* emb = (const float*)d_in[4];
  const float* scl = (const float*)d_in[5];

  float* out = (float*)d_out;
  float* out_quant = out;            // NTOK*3
  float* out_idx = out + 3 * NTOK;   // NTOK
  float* out_loss = out + 4 * NTOK;  // 1

  float4* cbf = (float4*)d_ws;                    // 65536 B
  float* statsf = (float*)((char*)d_ws + 65536);  // 64 B
  double* part = (double*)((char*)d_ws + 65600);  // NBLK*4*8 B

  hipLaunchKernelGGL(cb_kernel, dim3(VV / BS), dim3(BS), 0, stream, emb, cbf);
  hipLaunchKernelGGL(stats_kernel, dim3(8), dim3(BS), 0, stream, yh0, yh1, yh2, yl, statsf);
  hipLaunchKernelGGL(vq_kernel, dim3(NBLK), dim3(BS), 0, stream,
                     yh0, yh1, yh2, yl, emb, scl, cbf, statsf, out_quant, out_idx, part);
  hipLaunchKernelGGL(finalize_kernel, dim3(1), dim3(BS), 0, stream, part, out_loss);
}